// Round 2
// baseline (148.255 us; speedup 1.0000x reference)
//
#include <hip/hip_runtime.h>
#include <hip/hip_bf16.h>
#include <stdint.h>

typedef __attribute__((ext_vector_type(8))) short bf16x8;
typedef __attribute__((ext_vector_type(4))) float f32x4;

#define TWO_N 8192
#define NHALF 4096
#define DIM   128

// RNE f32 -> bf16 bits (inputs finite)
__device__ __forceinline__ unsigned int f2bf(float f) {
  unsigned int u = __float_as_uint(f);
  u += 0x7FFFu + ((u >> 16) & 1u);
  return u >> 16;
}

// ---------------- Kernel A: normalize rows of [zjs; zis] -> bf16 ----------------
__global__ __launch_bounds__(256) void norm_kernel(
    const float* __restrict__ zis, const float* __restrict__ zjs,
    unsigned int* __restrict__ rbf /* packed 2x bf16 per uint */) {
  const int wave = threadIdx.x >> 6;
  const int lane = threadIdx.x & 63;
  const int row = blockIdx.x * 4 + wave;
  const float* src = (row < NHALF) ? (zjs + (size_t)row * DIM)
                                   : (zis + (size_t)(row - NHALF) * DIM);
  float2 v = ((const float2*)src)[lane];
  float ss = v.x * v.x + v.y * v.y;
#pragma unroll
  for (int m = 1; m <= 32; m <<= 1) ss += __shfl_xor(ss, m);
  const float scale = 1.0f / fmaxf(sqrtf(ss), 1e-8f);
  const unsigned int lo = f2bf(v.x * scale);
  const unsigned int hi = f2bf(v.y * scale);
  rbf[(size_t)row * (DIM / 2) + lane] = lo | (hi << 16);
}

// async 16B global->LDS; LDS dest is wave-uniform-base + lane*16 (linear order)
#define GLL16(SRC, DST) __builtin_amdgcn_global_load_lds( \
    (__attribute__((address_space(1))) void*)(SRC),       \
    (__attribute__((address_space(3))) void*)(DST), 16, 0, 0)

// stage a 128-row x 256B tile (XOR-swizzle applied via pre-swizzled source addr)
#define STAGE128(ROWBASE, DST) do {                                        \
  _Pragma("unroll")                                                        \
  for (int i_ = 0; i_ < 8; ++i_) {                                         \
    const int L_ = (i_ * 256 + t) * 16;                                    \
    const int row_ = L_ >> 8;                                              \
    const int cb_ = L_ & 255;                                              \
    GLL16(rbytes + (size_t)((ROWBASE) + row_) * 256 +                      \
              (cb_ ^ ((row_ & 7) << 4)),                                   \
          (DST) + L_);                                                     \
  }                                                                        \
} while (0)

// ---------------- Kernel B: fused sim-tile GEMM + sum-of-exp ----------------
// grid = 512: rb = bid>>3 (row tile of 128), cs = bid&7 (col chunk of 1024)
// 1-deep pipelined B staging: Ab doubles as the second B buffer after the
// A fragments are hoisted to registers (LDS stays 64 KB -> 2 blocks/CU).
__global__ __launch_bounds__(256, 2) void simloss_kernel(
    char* __restrict__ rbytes,        // bf16 r matrix, row-major [8192][256B]
    float* __restrict__ pos,          // [8192] cosine sim with partner
    float* __restrict__ s_part) {     // [16][8192] partial sum-of-exp
  __shared__ char Ab[32768];
  __shared__ char Bb[32768];
  const int t = threadIdx.x;
  const int rb = blockIdx.x >> 3;
  const int cs = blockIdx.x & 7;
  const int RB = rb * 128;
  const int CS = cs * 1024;
  const int wave = t >> 6;
  const int lane = t & 63;
  const int wr = wave >> 1, wc = wave & 1;
  const int lrow = lane >> 4, lcol = lane & 15;

  STAGE128(RB, Ab);   // A tile
  STAGE128(CS, Bb);   // B(0)
  __syncthreads();    // drains vmcnt(0): both tiles resident

  // hoist A fragments into registers (Ab is then reused as a B buffer)
  bf16x8 a_reg[4][4];
#pragma unroll
  for (int ks = 0; ks < 4; ++ks)
#pragma unroll
    for (int m = 0; m < 4; ++m) {
      const int row = wr * 64 + m * 16 + lcol;
      const int kb = ks * 64 + lrow * 16;
      a_reg[ks][m] = *(const bf16x8*)(Ab + row * 256 + (kb ^ ((row & 7) << 4)));
    }
  __syncthreads();    // all waves done reading Ab before it is overwritten

  float srun[4][4];
#pragma unroll
  for (int m = 0; m < 4; ++m)
#pragma unroll
    for (int r = 0; r < 4; ++r) srun[m][r] = 0.0f;

#pragma unroll
  for (int ct = 0; ct < 8; ++ct) {
    char* curB = (ct & 1) ? Ab : Bb;   // B(ct) lives here (compile-time after unroll)
    char* nxtB = (ct & 1) ? Bb : Ab;
    if (ct < 7) STAGE128(CS + (ct + 1) * 128, nxtB);  // prefetch next B tile

    const int CB = CS + ct * 128;
    f32x4 acc[4][4];
#pragma unroll
    for (int m = 0; m < 4; ++m)
#pragma unroll
      for (int n = 0; n < 4; ++n) acc[m][n] = (f32x4){0.f, 0.f, 0.f, 0.f};

#pragma unroll
    for (int ks = 0; ks < 4; ++ks) {
      bf16x8 bfr[4];
#pragma unroll
      for (int n = 0; n < 4; ++n) {
        const int row = wc * 64 + n * 16 + lcol;
        const int kb = ks * 64 + lrow * 16;
        bfr[n] = *(const bf16x8*)(curB + row * 256 + (kb ^ ((row & 7) << 4)));
      }
#pragma unroll
      for (int m = 0; m < 4; ++m)
#pragma unroll
        for (int n = 0; n < 4; ++n)
          acc[m][n] = __builtin_amdgcn_mfma_f32_16x16x32_bf16(
              a_reg[ks][m], bfr[n], acc[m][n], 0, 0, 0);
    }

    // epilogue: logits z = 2*sim; accumulate exp(z) = exp2(sim * 2/ln2)
#pragma unroll
    for (int m = 0; m < 4; ++m) {
      const int R0 = RB + wr * 64 + m * 16;
#pragma unroll
      for (int n = 0; n < 4; ++n) {
        const int C0 = CB + wc * 64 + n * 16;
        const bool hasDiag = (C0 == R0);              // wave-uniform
        const bool hasPartner = (C0 == (R0 ^ 4096));  // wave-uniform
#pragma unroll
        for (int r = 0; r < 4; ++r) {
          const float v = acc[m][n][r];
          float e = __builtin_amdgcn_exp2f(v * 2.8853900817779268f);
          const bool mine = (lcol == lrow * 4 + r);
          if (hasPartner && mine) pos[R0 + lrow * 4 + r] = v;
          if (hasDiag && mine) e = 0.0f;
          srun[m][r] += e;
        }
      }
    }
    __syncthreads();  // B(ct+1) landed (vmcnt drain) AND all waves done with curB
  }

  // butterfly-sum across the 16 lanes sharing each output row, store partials
#pragma unroll
  for (int m = 0; m < 4; ++m)
#pragma unroll
    for (int r = 0; r < 4; ++r) {
      float s = srun[m][r];
      s += __shfl_xor(s, 1);
      s += __shfl_xor(s, 2);
      s += __shfl_xor(s, 4);
      s += __shfl_xor(s, 8);
      if (lcol == 0)
        s_part[(size_t)(cs * 2 + wc) * TWO_N +
               (RB + wr * 64 + m * 16 + lrow * 4 + r)] = s;
    }
}

// ---------------- Kernel C1: per-row loss, 32-block partial sums ----------------
__global__ __launch_bounds__(256) void reduce1_kernel(
    const float* __restrict__ pos, const float* __restrict__ s_part,
    float* __restrict__ partial) {
  const int t = threadIdx.x;
  const int row = blockIdx.x * 256 + t;
  float s = 0.0f;
#pragma unroll
  for (int q = 0; q < 16; ++q) s += s_part[(size_t)q * TWO_N + row];
  float local = __logf(s) - 2.0f * pos[row];
#pragma unroll
  for (int m = 1; m <= 32; m <<= 1) local += __shfl_xor(local, m);
  __shared__ float wsum[4];
  if ((t & 63) == 0) wsum[t >> 6] = local;
  __syncthreads();
  if (t == 0) partial[blockIdx.x] = wsum[0] + wsum[1] + wsum[2] + wsum[3];
}

// ---------------- Kernel C2: combine 32 partials -> scalar ----------------
__global__ __launch_bounds__(64) void reduce2_kernel(
    const float* __restrict__ partial, float* __restrict__ out) {
  float v = (threadIdx.x < 32) ? partial[threadIdx.x] : 0.0f;
#pragma unroll
  for (int m = 1; m <= 32; m <<= 1) v += __shfl_xor(v, m);
  if (threadIdx.x == 0) out[0] = v * (1.0f / TWO_N);
}

extern "C" void kernel_launch(void* const* d_in, const int* in_sizes, int n_in,
                              void* d_out, int out_size, void* d_ws, size_t ws_size,
                              hipStream_t stream) {
  const float* zis = (const float*)d_in[0];
  const float* zjs = (const float*)d_in[1];
  char* ws = (char*)d_ws;
  unsigned int* rbf = (unsigned int*)ws;                          // 2 MB: bf16 r
  float* pos = (float*)(ws + 2u * 1024 * 1024);                   // 32 KB
  float* s_part = (float*)(ws + 2u * 1024 * 1024 + 32 * 1024);    // 512 KB
  float* partial = (float*)(ws + 2u * 1024 * 1024 + 32 * 1024 + 512 * 1024);  // 128 B

  norm_kernel<<<TWO_N / 4, 256, 0, stream>>>(zis, zjs, rbf);
  simloss_kernel<<<512, 256, 0, stream>>>((char*)rbf, pos, s_part);
  reduce1_kernel<<<TWO_N / 256, 256, 0, stream>>>(pos, s_part, partial);
  reduce2_kernel<<<1, 64, 0, stream>>>(partial, (float*)d_out);
}

// Round 3
// 85.888 us; speedup vs baseline: 1.7261x; 1.7261x over previous
//
#include <hip/hip_runtime.h>
#include <hip/hip_bf16.h>
#include <stdint.h>

typedef __attribute__((ext_vector_type(8))) short bf16x8;
typedef __attribute__((ext_vector_type(4))) float f32x4;

#define TWO_N 8192
#define NHALF 4096
#define DIM   128

// sqrt(2 / (tau * ln2)) with tau = 0.5 : rows pre-scaled so dot = logit/ln2
#define SQRT_C 1.69864361f
#define LN2    0.69314718055994531f

// RNE f32 -> bf16 bits (inputs finite)
__device__ __forceinline__ unsigned int f2bf(float f) {
  unsigned int u = __float_as_uint(f);
  u += 0x7FFFu + ((u >> 16) & 1u);
  return u >> 16;
}

// ---------------- Kernel A: normalize+prescale rows of [zjs; zis] -> bf16 ----------------
__global__ __launch_bounds__(256) void norm_kernel(
    const float* __restrict__ zis, const float* __restrict__ zjs,
    unsigned int* __restrict__ rbf /* packed 2x bf16 per uint */) {
  const int wave = threadIdx.x >> 6;
  const int lane = threadIdx.x & 63;
  const int row = blockIdx.x * 4 + wave;
  const float* src = (row < NHALF) ? (zjs + (size_t)row * DIM)
                                   : (zis + (size_t)(row - NHALF) * DIM);
  float2 v = ((const float2*)src)[lane];
  float ss = v.x * v.x + v.y * v.y;
#pragma unroll
  for (int m = 1; m <= 32; m <<= 1) ss += __shfl_xor(ss, m);
  const float scale = SQRT_C / fmaxf(sqrtf(ss), 1e-8f);
  const unsigned int lo = f2bf(v.x * scale);
  const unsigned int hi = f2bf(v.y * scale);
  rbf[(size_t)row * (DIM / 2) + lane] = lo | (hi << 16);
}

// async 16B global->LDS; LDS dest is wave-uniform-base + lane*16 (linear order)
#define GLL16(SRC, DST) __builtin_amdgcn_global_load_lds( \
    (__attribute__((address_space(1))) void*)(SRC),       \
    (__attribute__((address_space(3))) void*)(DST), 16, 0, 0)

// stage a 128-row x 256B tile (XOR-swizzle applied via pre-swizzled source addr)
#define STAGE128(ROWBASE, DST) do {                                        \
  _Pragma("unroll")                                                        \
  for (int i_ = 0; i_ < 8; ++i_) {                                         \
    const int L_ = (i_ * 256 + t) * 16;                                    \
    const int row_ = L_ >> 8;                                              \
    const int cb_ = L_ & 255;                                              \
    GLL16(rbytes + (size_t)((ROWBASE) + row_) * 256 +                      \
              (cb_ ^ ((row_ & 7) << 4)),                                   \
          (DST) + L_);                                                     \
  }                                                                        \
} while (0)

// ---------------- Kernel B: fused sim-tile GEMM + sum-of-exp ----------------
// grid = 512: rb = bid>>3 (row tile of 128), cs = bid&7 (col chunk of 1024)
// Ab doubles as the second B buffer once a_reg is hoisted (LDS = 64 KB,
// 2 blocks/CU). waves_per_eu pinned to 2 -> 256 VGPR cap -> no spills.
__global__ __launch_bounds__(256)
__attribute__((amdgpu_waves_per_eu(2, 2)))
void simloss_kernel(
    char* __restrict__ rbytes,        // bf16 r matrix, row-major [8192][256B]
    float* __restrict__ pos,          // [8192] v = logit/ln2 for partner
    float* __restrict__ s_part) {     // [16][8192] partial sum-of-exp
  __shared__ char Ab[32768];
  __shared__ char Bb[32768];
  const int t = threadIdx.x;
  const int rb = blockIdx.x >> 3;
  const int cs = blockIdx.x & 7;
  const int RB = rb * 128;
  const int CS = cs * 1024;
  const int wave = t >> 6;
  const int lane = t & 63;
  const int wr = wave >> 1, wc = wave & 1;
  const int lrow = lane >> 4, lcol = lane & 15;

  STAGE128(RB, Ab);   // A tile
  STAGE128(CS, Bb);   // B(0)
  __syncthreads();    // drains vmcnt(0): both tiles resident

  // hoist A fragments into registers (Ab is then reused as a B buffer)
  bf16x8 a_reg[4][4];
#pragma unroll
  for (int ks = 0; ks < 4; ++ks)
#pragma unroll
    for (int m = 0; m < 4; ++m) {
      const int row = wr * 64 + m * 16 + lcol;
      const int kb = ks * 64 + lrow * 16;
      a_reg[ks][m] = *(const bf16x8*)(Ab + row * 256 + (kb ^ ((row & 7) << 4)));
    }
  __syncthreads();    // all waves done reading Ab before it is overwritten

  float srun[4][4];
#pragma unroll
  for (int m = 0; m < 4; ++m)
#pragma unroll
    for (int r = 0; r < 4; ++r) srun[m][r] = 0.0f;

  char* curB = Bb;
  char* nxtB = Ab;
#pragma unroll 1
  for (int ct = 0; ct < 8; ++ct) {
    if (ct < 7) STAGE128(CS + (ct + 1) * 128, nxtB);  // prefetch next B tile

    const int CB = CS + ct * 128;
    f32x4 acc[4][4];
#pragma unroll
    for (int m = 0; m < 4; ++m)
#pragma unroll
      for (int n = 0; n < 4; ++n) acc[m][n] = (f32x4){0.f, 0.f, 0.f, 0.f};

#pragma unroll
    for (int ks = 0; ks < 4; ++ks) {
      bf16x8 bfr[4];
#pragma unroll
      for (int n = 0; n < 4; ++n) {
        const int row = wc * 64 + n * 16 + lcol;
        const int kb = ks * 64 + lrow * 16;
        bfr[n] = *(const bf16x8*)(curB + row * 256 + (kb ^ ((row & 7) << 4)));
      }
#pragma unroll
      for (int m = 0; m < 4; ++m)
#pragma unroll
        for (int n = 0; n < 4; ++n)
          acc[m][n] = __builtin_amdgcn_mfma_f32_16x16x32_bf16(
              a_reg[ks][m], bfr[n], acc[m][n], 0, 0, 0);
    }

    // epilogue: v = logit/ln2 directly (rows pre-scaled); sum exp2(v)
#pragma unroll
    for (int m = 0; m < 4; ++m) {
      const int R0 = RB + wr * 64 + m * 16;
#pragma unroll
      for (int n = 0; n < 4; ++n) {
        const int C0 = CB + wc * 64 + n * 16;
        const bool hasDiag = (C0 == R0);              // wave-uniform
        const bool hasPartner = (C0 == (R0 ^ 4096));  // wave-uniform
#pragma unroll
        for (int r = 0; r < 4; ++r) {
          const float v = acc[m][n][r];
          float e = __builtin_amdgcn_exp2f(v);
          const bool mine = (lcol == lrow * 4 + r);
          if (hasPartner && mine) pos[R0 + lrow * 4 + r] = v;
          if (hasDiag && mine) e = 0.0f;
          srun[m][r] += e;
        }
      }
    }
    __syncthreads();  // B(ct+1) landed (vmcnt drain) AND all waves done with curB
    char* tmp = curB; curB = nxtB; nxtB = tmp;
  }

  // butterfly-sum across the 16 lanes sharing each output row, store partials
#pragma unroll
  for (int m = 0; m < 4; ++m)
#pragma unroll
    for (int r = 0; r < 4; ++r) {
      float s = srun[m][r];
      s += __shfl_xor(s, 1);
      s += __shfl_xor(s, 2);
      s += __shfl_xor(s, 4);
      s += __shfl_xor(s, 8);
      if (lcol == 0)
        s_part[(size_t)(cs * 2 + wc) * TWO_N +
               (RB + wr * 64 + m * 16 + lrow * 4 + r)] = s;
    }
}

// ---------------- Kernel C1: per-row loss, 32-block partial sums ----------------
__global__ __launch_bounds__(256) void reduce1_kernel(
    const float* __restrict__ pos, const float* __restrict__ s_part,
    float* __restrict__ partial) {
  const int t = threadIdx.x;
  const int row = blockIdx.x * 256 + t;
  float s = 0.0f;
#pragma unroll
  for (int q = 0; q < 16; ++q) s += s_part[(size_t)q * TWO_N + row];
  // loss_row = ln(s) - 2*sim_pos = ln2 * (log2(s) - v_pos)
  float local = (__log2f(s) - pos[row]) * LN2;
#pragma unroll
  for (int m = 1; m <= 32; m <<= 1) local += __shfl_xor(local, m);
  __shared__ float wsum[4];
  if ((t & 63) == 0) wsum[t >> 6] = local;
  __syncthreads();
  if (t == 0) partial[blockIdx.x] = wsum[0] + wsum[1] + wsum[2] + wsum[3];
}

// ---------------- Kernel C2: combine 32 partials -> scalar ----------------
__global__ __launch_bounds__(64) void reduce2_kernel(
    const float* __restrict__ partial, float* __restrict__ out) {
  float v = (threadIdx.x < 32) ? partial[threadIdx.x] : 0.0f;
#pragma unroll
  for (int m = 1; m <= 32; m <<= 1) v += __shfl_xor(v, m);
  if (threadIdx.x == 0) out[0] = v * (1.0f / TWO_N);
}

extern "C" void kernel_launch(void* const* d_in, const int* in_sizes, int n_in,
                              void* d_out, int out_size, void* d_ws, size_t ws_size,
                              hipStream_t stream) {
  const float* zis = (const float*)d_in[0];
  const float* zjs = (const float*)d_in[1];
  char* ws = (char*)d_ws;
  unsigned int* rbf = (unsigned int*)ws;                          // 2 MB: bf16 r
  float* pos = (float*)(ws + 2u * 1024 * 1024);                   // 32 KB
  float* s_part = (float*)(ws + 2u * 1024 * 1024 + 32 * 1024);    // 512 KB
  float* partial = (float*)(ws + 2u * 1024 * 1024 + 32 * 1024 + 512 * 1024);  // 128 B

  norm_kernel<<<TWO_N / 4, 256, 0, stream>>>(zis, zjs, rbf);
  simloss_kernel<<<512, 256, 0, stream>>>((char*)rbf, pos, s_part);
  reduce1_kernel<<<TWO_N / 256, 256, 0, stream>>>(pos, s_part, partial);
  reduce2_kernel<<<1, 64, 0, stream>>>(partial, (float*)d_out);
}